// Round 4
// baseline (1047.262 us; speedup 1.0000x reference)
//
#include <hip/hip_runtime.h>
#include <hip/hip_cooperative_groups.h>
#include <hip/hip_bf16.h>
#include <cstdint>
#include <cstddef>

namespace cg = cooperative_groups;

#define N_NODES 262144
#define NGRAPH  2048
#define DIM     512
#define OUTD    128

typedef __attribute__((ext_vector_type(8))) short  short8;
typedef __attribute__((ext_vector_type(4))) float  floatx4;

__device__ inline unsigned short f2bf(float f) {
    union { float f; uint32_t u; } v; v.f = f;
    uint32_t u = v.u;
    return (unsigned short)((u + 0x7fffu + ((u >> 16) & 1u)) >> 16);
}
__device__ inline float bf2f(unsigned short h) {
    union { uint32_t u; float f; } v; v.u = ((uint32_t)h) << 16; return v.f;
}
__device__ __forceinline__ void gload_lds16(const void* g, void* l) {
    __builtin_amdgcn_global_load_lds((const __attribute__((address_space(1))) void*)g,
                                     (__attribute__((address_space(3))) void*)l, 16, 0, 0);
}
__device__ __forceinline__ int lbound(const int* __restrict__ seg, int b) {
    int lo = 0, hi = N_NODES;
    while (lo < hi) { int mid = (lo + hi) >> 1; if (seg[mid] < b) lo = mid + 1; else hi = mid; }
    return lo;
}

// ---- single-buffered 128x64 MFMA tile, BK=64, same swizzle geometry as R2 ----
__device__ __forceinline__ void gemm_tile(char* smem, int t, int mbase, int nbase,
        const unsigned short* __restrict__ A, const unsigned short* __restrict__ B,
        unsigned short* __restrict__ Cbf, float* __restrict__ Cf, int Ccols) {
    int w = t >> 6, lane = t & 63;
    int wr = w >> 1, wc = w & 1;
    int fr = lane & 15, hi4 = lane >> 4;
    int swz = (fr & 7) << 4;
    int rbase = t >> 3;
    int cole = ((((t & 7) * 16) ^ ((rbase & 7) << 4)) >> 1);
    int ldsoff = t * 16;
    floatx4 acc[4][2];
    #pragma unroll
    for (int m = 0; m < 4; m++)
        #pragma unroll
        for (int n = 0; n < 2; n++) {
            acc[m][n][0] = 0.f; acc[m][n][1] = 0.f; acc[m][n][2] = 0.f; acc[m][n][3] = 0.f;
        }
    const unsigned short* gA = A + (size_t)(mbase + rbase) * DIM + cole;
    const unsigned short* gW = B + (size_t)(nbase + rbase) * DIM + cole;
    char* lA = smem;
    char* lW = smem + 16384;
    for (int it = 0; it < 8; ++it) {
        int kk = it * 64;
        if (it) __syncthreads();
        #pragma unroll
        for (int c = 0; c < 4; ++c)
            gload_lds16(gA + (size_t)(c * 32) * DIM + kk, lA + c * 4096 + ldsoff);
        #pragma unroll
        for (int c = 0; c < 2; ++c)
            gload_lds16(gW + (size_t)(c * 32) * DIM + kk, lW + c * 4096 + ldsoff);
        __syncthreads();
        #pragma unroll
        for (int ks = 0; ks < 2; ++ks) {
            short8 af[4], bv[2];
            int bc = (ks * 64 + hi4 * 16) ^ swz;
            #pragma unroll
            for (int m = 0; m < 4; ++m)
                af[m] = *reinterpret_cast<const short8*>(lA + (wr * 64 + m * 16 + fr) * 128 + bc);
            #pragma unroll
            for (int n = 0; n < 2; ++n)
                bv[n] = *reinterpret_cast<const short8*>(lW + (wc * 32 + n * 16 + fr) * 128 + bc);
            #pragma unroll
            for (int m = 0; m < 4; ++m)
                #pragma unroll
                for (int n = 0; n < 2; ++n)
                    acc[m][n] = __builtin_amdgcn_mfma_f32_16x16x32_bf16(af[m], bv[n], acc[m][n], 0, 0, 0);
        }
    }
    int rq = hi4 * 4;
    #pragma unroll
    for (int m = 0; m < 4; m++)
        #pragma unroll
        for (int n = 0; n < 2; n++) {
            int col = nbase + wc * 32 + n * 16 + fr;
            #pragma unroll
            for (int r = 0; r < 4; r++) {
                int row = mbase + wr * 64 + m * 16 + rq + r;
                float v = acc[m][n][r];
                if (Cbf) {
                    v = v > 0.f ? v : (__expf(v) - 1.0f);
                    Cbf[(size_t)row * Ccols + col] = f2bf(v);
                } else {
                    Cf[(size_t)row * Ccols + col] = v;
                }
            }
        }
    __syncthreads();
}

__global__ __launch_bounds__(256, 4) void k_all(
        const float* __restrict__ x, const int* __restrict__ seg,
        const float* __restrict__ watl, const float* __restrict__ watr,
        const float* __restrict__ Wnode, const float* __restrict__ Wih,
        const float* __restrict__ Whh, const float* __restrict__ bih,
        const float* __restrict__ bhh, const float* __restrict__ Wlin,
        const float* __restrict__ blin, float* __restrict__ out,
        float* __restrict__ left, float* __restrict__ hcur,
        unsigned short* __restrict__ hcurbf, unsigned short* __restrict__ hgbf,
        unsigned short* __restrict__ swbf, float* __restrict__ gi,
        float* __restrict__ gh, unsigned short* __restrict__ WnT,
        unsigned short* __restrict__ Wihb, unsigned short* __restrict__ Whhb,
        unsigned short* __restrict__ xbf, int* __restrict__ starts,
        int use_xbf) {
    cg::grid_group gg = cg::this_grid();
    __shared__ __align__(16) char smem[32768];
    const int t = threadIdx.x;
    const int blk = blockIdx.x;
    const int NB = gridDim.x;
    const int w = t >> 6, lane = t & 63;

    //================ Phase A: weight prep + graph starts ================
    {   // WnT transpose (tiles of 32x32)
        float (*tile)[33] = reinterpret_cast<float (*)[33]>(smem);
        int tx = t & 31, ty = t >> 5;
        for (int tl = blk; tl < 256; tl += NB) {
            int bx = tl >> 4, by = tl & 15;
            #pragma unroll
            for (int r = 0; r < 32; r += 8)
                tile[ty + r][tx] = Wnode[(size_t)(bx * 32 + ty + r) * DIM + by * 32 + tx];
            __syncthreads();
            #pragma unroll
            for (int r = 0; r < 32; r += 8)
                WnT[(size_t)(by * 32 + ty + r) * DIM + bx * 32 + tx] = f2bf(tile[tx][ty + r]);
            __syncthreads();
        }
    }
    {   // Wih/Whh -> bf16, graph starts
        int gid = blk * 256 + t;
        const int TOT4 = (1536 * DIM) / 4;
        for (int i = gid; i < TOT4; i += NB * 256) {
            float4 a = reinterpret_cast<const float4*>(Wih)[i];
            ushort4 o; o.x = f2bf(a.x); o.y = f2bf(a.y); o.z = f2bf(a.z); o.w = f2bf(a.w);
            reinterpret_cast<ushort4*>(Wihb)[i] = o;
            float4 c = reinterpret_cast<const float4*>(Whh)[i];
            ushort4 o2; o2.x = f2bf(c.x); o2.y = f2bf(c.y); o2.z = f2bf(c.z); o2.w = f2bf(c.w);
            reinterpret_cast<ushort4*>(Whhb)[i] = o2;
        }
        if (gid <= NGRAPH) starts[gid] = lbound(seg, gid);
    }
    gg.sync();

    //================ Phase B: init (sum-pool h0, left_att, x->bf16) ================
    {
        float* wl  = reinterpret_cast<float*>(smem);         // 512 f
        float* red = reinterpret_cast<float*>(smem) + DIM;   // 2048 f
        int f0 = lane * 4;
        for (int b = blk; b < NGRAPH; b += NB) {
            wl[t] = watl[t]; wl[t + 256] = watl[t + 256];
            int s = starts[b], e = starts[b + 1];
            __syncthreads();
            float acc[8] = {0.f,0.f,0.f,0.f,0.f,0.f,0.f,0.f};
            for (int i = s + w; i < e; i += 4) {
                float4 v0 = *reinterpret_cast<const float4*>(x + (size_t)i * DIM + f0);
                float4 v1 = *reinterpret_cast<const float4*>(x + (size_t)i * DIM + 256 + f0);
                acc[0] += v0.x; acc[1] += v0.y; acc[2] += v0.z; acc[3] += v0.w;
                acc[4] += v1.x; acc[5] += v1.y; acc[6] += v1.z; acc[7] += v1.w;
                float dot = v0.x*wl[f0] + v0.y*wl[f0+1] + v0.z*wl[f0+2] + v0.w*wl[f0+3]
                          + v1.x*wl[256+f0] + v1.y*wl[256+f0+1] + v1.z*wl[256+f0+2] + v1.w*wl[256+f0+3];
                #pragma unroll
                for (int off = 32; off > 0; off >>= 1) dot += __shfl_xor(dot, off);
                if (lane == 0) left[i] = dot;
                if (use_xbf) {
                    ushort4 o0, o1;
                    o0.x = f2bf(v0.x); o0.y = f2bf(v0.y); o0.z = f2bf(v0.z); o0.w = f2bf(v0.w);
                    o1.x = f2bf(v1.x); o1.y = f2bf(v1.y); o1.z = f2bf(v1.z); o1.w = f2bf(v1.w);
                    *reinterpret_cast<ushort4*>(xbf + (size_t)i * DIM + f0) = o0;
                    *reinterpret_cast<ushort4*>(xbf + (size_t)i * DIM + 256 + f0) = o1;
                }
            }
            #pragma unroll
            for (int j = 0; j < 4; j++) {
                red[w * DIM + f0 + j]       = acc[j];
                red[w * DIM + 256 + f0 + j] = acc[4 + j];
            }
            __syncthreads();
            float s0 = red[t]       + red[DIM + t]       + red[2*DIM + t]       + red[3*DIM + t];
            float s1 = red[256 + t] + red[DIM + 256 + t] + red[2*DIM + 256 + t] + red[3*DIM + 256 + t];
            hcur[(size_t)b * DIM + t] = s0;
            hcur[(size_t)b * DIM + 256 + t] = s1;
            hcurbf[(size_t)b * DIM + t] = f2bf(s0);
            hcurbf[(size_t)b * DIM + 256 + t] = f2bf(s1);
            __syncthreads();
        }
    }
    gg.sync();

    for (int ts = 0; ts < 2; ++ts) {
        //================ att: right-att dot + segment softmax + weighted sum ================
        {
            float* red = reinterpret_cast<float*>(smem);          // 2048 f
            float* rsc = reinterpret_cast<float*>(smem) + 2048;   // 8 f
            for (int b = blk; b < NGRAPH; b += NB) {
                float p = hcur[(size_t)b * DIM + t] * watr[t]
                        + hcur[(size_t)b * DIM + 256 + t] * watr[256 + t];
                red[t] = p; __syncthreads();
                for (int off = 128; off > 0; off >>= 1) { if (t < off) red[t] += red[t + off]; __syncthreads(); }
                float ra = red[0];
                __syncthreads();
                int s = starts[b], e = starts[b + 1];
                float m = -1e30f;
                for (int i = s + t; i < e; i += 256) {
                    float a = left[i] + ra; a = a >= 0.f ? a : 0.01f * a;
                    m = fmaxf(m, a);
                }
                red[t] = m; __syncthreads();
                for (int off = 128; off > 0; off >>= 1) { if (t < off) red[t] = fmaxf(red[t], red[t + off]); __syncthreads(); }
                m = red[0];
                __syncthreads();
                float acc[8] = {0.f,0.f,0.f,0.f,0.f,0.f,0.f,0.f};
                float esum = 0.f;
                if (use_xbf) {
                    int f0 = lane * 8;
                    for (int i = s + w; i < e; i += 4) {
                        float a = left[i] + ra; a = a >= 0.f ? a : 0.01f * a;
                        float ev = __expf(a - m);
                        esum += ev;
                        short8 v = *reinterpret_cast<const short8*>(xbf + (size_t)i * DIM + f0);
                        #pragma unroll
                        for (int j = 0; j < 8; j++) acc[j] += ev * bf2f((unsigned short)v[j]);
                    }
                    #pragma unroll
                    for (int j = 0; j < 8; j++) red[w * DIM + f0 + j] = acc[j];
                } else {
                    int f0 = lane * 4;
                    for (int i = s + w; i < e; i += 4) {
                        float a = left[i] + ra; a = a >= 0.f ? a : 0.01f * a;
                        float ev = __expf(a - m);
                        esum += ev;
                        float4 v0 = *reinterpret_cast<const float4*>(x + (size_t)i * DIM + f0);
                        float4 v1 = *reinterpret_cast<const float4*>(x + (size_t)i * DIM + 256 + f0);
                        acc[0] += ev * v0.x; acc[1] += ev * v0.y; acc[2] += ev * v0.z; acc[3] += ev * v0.w;
                        acc[4] += ev * v1.x; acc[5] += ev * v1.y; acc[6] += ev * v1.z; acc[7] += ev * v1.w;
                    }
                    #pragma unroll
                    for (int j = 0; j < 4; j++) {
                        red[w * DIM + f0 + j]       = acc[j];
                        red[w * DIM + 256 + f0 + j] = acc[4 + j];
                    }
                }
                if (lane == 0) rsc[w] = esum;
                __syncthreads();
                float tot = rsc[0] + rsc[1] + rsc[2] + rsc[3];
                float inv = tot > 0.f ? 1.0f / tot : 0.0f;
                float s0 = (red[t]       + red[DIM + t]       + red[2*DIM + t]       + red[3*DIM + t])       * inv;
                float s1 = (red[256 + t] + red[DIM + 256 + t] + red[2*DIM + 256 + t] + red[3*DIM + 256 + t]) * inv;
                swbf[(size_t)b * DIM + t] = f2bf(s0);
                swbf[(size_t)b * DIM + 256 + t] = f2bf(s1);
                __syncthreads();
            }
        }
        gg.sync();

        //================ gemm1: hg = elu(sw @ WnT^T) -> bf16 (16 x 8 tiles) ================
        for (int tl = blk; tl < 128; tl += NB) {
            int mbase = (tl >> 3) * 128;
            int nbase = (tl & 7) * 64;
            gemm_tile(smem, t, mbase, nbase, swbf, WnT, hgbf, nullptr, DIM);
        }
        gg.sync();

        //================ gemmz: gi = hg@Wih^T, gh = h@Whh^T (16 x 24 x 2 tiles) ================
        for (int tl = blk; tl < 768; tl += NB) {
            int z = (tl >= 384) ? 1 : 0;
            int tz = tl - z * 384;
            int mbase = (tz & 15) * 128;
            int nbase = (tz >> 4) * 64;
            const unsigned short* A = z ? hcurbf : hgbf;
            const unsigned short* B = z ? Whhb : Wihb;
            float* C = z ? gh : gi;
            gemm_tile(smem, t, mbase, nbase, A, B, nullptr, C, 1536);
        }
        gg.sync();

        //================ gate: GRU gates + silu ================
        {
            int base = blk * 256 + t;
            for (int idx = base; idx < NGRAPH * DIM; idx += NB * 256) {
                int b = idx >> 9, j = idx & 511;
                size_t gb = (size_t)b * 1536;
                float gir = gi[gb + j]        + bih[j];
                float giz = gi[gb + 512 + j]  + bih[512 + j];
                float gin = gi[gb + 1024 + j] + bih[1024 + j];
                float ghr = gh[gb + j]        + bhh[j];
                float ghz = gh[gb + 512 + j]  + bhh[512 + j];
                float ghn = gh[gb + 1024 + j] + bhh[1024 + j];
                float r = 1.0f / (1.0f + __expf(-(gir + ghr)));
                float zg = 1.0f / (1.0f + __expf(-(giz + ghz)));
                float n = tanhf(gin + r * ghn);
                float h = hcur[(size_t)b * DIM + j];
                float nh = (1.0f - zg) * n + zg * h;
                float o = nh / (1.0f + __expf(-nh));
                hcur[(size_t)b * DIM + j] = o;
                hcurbf[(size_t)b * DIM + j] = f2bf(o);
            }
        }
        gg.sync();
    }

    //================ fin: out = hcur @ W_lin + b_lin (128 tiles of 16 graphs) ================
    {
        float* rows = reinterpret_cast<float*>(smem);   // 16*512 f = 32 KB
        for (int tl = blk; tl < NGRAPH / 16; tl += NB) {
            int b0 = tl * 16;
            for (int i = t; i < 16 * DIM / 4; i += 256)
                reinterpret_cast<float4*>(rows)[i] =
                    reinterpret_cast<const float4*>(hcur + (size_t)b0 * DIM)[i];
            __syncthreads();
            int col = t & 127, rg = t >> 7;
            float acc[8];
            #pragma unroll
            for (int r = 0; r < 8; r++) acc[r] = 0.f;
            #pragma unroll 4
            for (int k = 0; k < DIM; k++) {
                float wv = Wlin[k * OUTD + col];
                #pragma unroll
                for (int r = 0; r < 8; r++) acc[r] += rows[(rg * 8 + r) * DIM + k] * wv;
            }
            float bl = blin[col];
            #pragma unroll
            for (int r = 0; r < 8; r++)
                out[(size_t)(b0 + rg * 8 + r) * OUTD + col] = acc[r] + bl;
            __syncthreads();
        }
    }
}

extern "C" void kernel_launch(void* const* d_in, const int* in_sizes, int n_in,
                              void* d_out, int out_size, void* d_ws, size_t ws_size,
                              hipStream_t stream) {
    const float* x     = (const float*)d_in[0];
    const int*   seg   = (const int*)d_in[1];
    const float* watl  = (const float*)d_in[2];
    const float* watr  = (const float*)d_in[3];
    const float* Wnode = (const float*)d_in[4];
    const float* Wih   = (const float*)d_in[5];
    const float* Whh   = (const float*)d_in[6];
    const float* bih   = (const float*)d_in[7];
    const float* bhh   = (const float*)d_in[8];
    const float* Wlin  = (const float*)d_in[9];
    const float* blin  = (const float*)d_in[10];
    float* out = (float*)d_out;

    char* ws = (char*)d_ws;
    size_t off = 0;
    auto alloc = [&](size_t bytes) -> void* {
        void* p = ws + off;
        off += bytes;
        off = (off + 255) & ~(size_t)255;
        return p;
    };
    float*          left    = (float*)          alloc((size_t)N_NODES * sizeof(float));
    float*          hcur    = (float*)          alloc((size_t)NGRAPH * DIM * sizeof(float));
    unsigned short* hcurbf  = (unsigned short*) alloc((size_t)NGRAPH * DIM * 2);
    unsigned short* hgbf    = (unsigned short*) alloc((size_t)NGRAPH * DIM * 2);
    unsigned short* swbf    = (unsigned short*) alloc((size_t)NGRAPH * DIM * 2);
    float*          gi      = (float*)          alloc((size_t)NGRAPH * 1536 * sizeof(float));
    float*          gh      = (float*)          alloc((size_t)NGRAPH * 1536 * sizeof(float));
    unsigned short* WnT     = (unsigned short*) alloc((size_t)DIM * DIM * 2);
    unsigned short* Wihb    = (unsigned short*) alloc((size_t)1536 * DIM * 2);
    unsigned short* Whhb    = (unsigned short*) alloc((size_t)1536 * DIM * 2);
    int*            starts  = (int*)            alloc((NGRAPH + 1) * sizeof(int));
    unsigned short* xbf     = (unsigned short*)(ws + off);
    int use_xbf = (off + (size_t)N_NODES * DIM * 2) <= ws_size ? 1 : 0;

    int nb = 0;
    hipError_t oe = hipOccupancyMaxActiveBlocksPerMultiprocessor(&nb, k_all, 256, 0);
    if (oe != hipSuccess || nb < 1) nb = 2;
    int grid = nb * 256;               // 256 CUs on MI355X
    if (grid > 1024) grid = 1024;

    void* args[] = {
        (void*)&x, (void*)&seg, (void*)&watl, (void*)&watr, (void*)&Wnode,
        (void*)&Wih, (void*)&Whh, (void*)&bih, (void*)&bhh, (void*)&Wlin,
        (void*)&blin, (void*)&out, (void*)&left, (void*)&hcur, (void*)&hcurbf,
        (void*)&hgbf, (void*)&swbf, (void*)&gi, (void*)&gh, (void*)&WnT,
        (void*)&Wihb, (void*)&Whhb, (void*)&xbf, (void*)&starts, (void*)&use_xbf
    };
    hipLaunchCooperativeKernel(reinterpret_cast<void*>(k_all), dim3(grid), dim3(256),
                               args, 0, stream);
}

// Round 5
// 349.453 us; speedup vs baseline: 2.9969x; 2.9969x over previous
//
#include <hip/hip_runtime.h>
#include <hip/hip_bf16.h>
#include <cstdint>
#include <cstddef>

#define N_NODES 262144
#define NGRAPH  2048
#define DIM     512
#define HID3    1536
#define OUTD    128

typedef __attribute__((ext_vector_type(8))) short  short8;
typedef __attribute__((ext_vector_type(4))) float  floatx4;
typedef __attribute__((ext_vector_type(2))) float  floatx2;

__device__ inline unsigned short f2bf(float f) {
    union { float f; uint32_t u; } v; v.f = f;
    uint32_t u = v.u;
    return (unsigned short)((u + 0x7fffu + ((u >> 16) & 1u)) >> 16);
}
__device__ inline float bf2f(unsigned short h) {
    union { uint32_t u; float f; } v; v.u = ((uint32_t)h) << 16; return v.f;
}

__device__ __forceinline__ void gload_lds16(const void* g, void* l) {
    __builtin_amdgcn_global_load_lds((const __attribute__((address_space(1))) void*)g,
                                     (__attribute__((address_space(3))) void*)l, 16, 0, 0);
}

// ---------------- prep: weight converts + transpose + graph starts ----------------
__global__ __launch_bounds__(256) void k_prep(const float* __restrict__ Wih,
        const float* __restrict__ Whh, const float* __restrict__ Wnode,
        const int* __restrict__ seg, unsigned short* __restrict__ Wihb,
        unsigned short* __restrict__ Whhb, unsigned short* __restrict__ WnT,
        int* __restrict__ starts) {
    __shared__ float tile[32][33];
    int id = blockIdx.x, t = threadIdx.x;
    if (id < 3072) {
        int i = id * 256 + t; Wihb[i] = f2bf(Wih[i]);
    } else if (id < 6144) {
        int i = (id - 3072) * 256 + t; Whhb[i] = f2bf(Whh[i]);
    } else if (id < 6400) {
        int idx = id - 6144;
        int bx = idx >> 4, by = idx & 15;
        int tx = t & 31, ty = t >> 5;
        for (int r = 0; r < 32; r += 8)
            tile[ty + r][tx] = Wnode[(size_t)(bx * 32 + ty + r) * DIM + by * 32 + tx];
        __syncthreads();
        for (int r = 0; r < 32; r += 8)
            WnT[(size_t)(by * 32 + ty + r) * DIM + bx * 32 + tx] = f2bf(tile[tx][ty + r]);
    } else {
        int b = (id - 6400) * 256 + t;
        if (b <= NGRAPH) {
            int lo = 0, hi = N_NODES;
            while (lo < hi) { int mid = (lo + hi) >> 1; if (seg[mid] < b) lo = mid + 1; else hi = mid; }
            starts[b] = lo;
        }
    }
}

// ---------------- init: sum-pool h0, left_att, x->fp8 cache ----------------
template<bool WRITE_XQ>
__global__ __launch_bounds__(256) void k_init(const float* __restrict__ x,
        const int* __restrict__ starts, const float* __restrict__ watl,
        float* __restrict__ left_att, float* __restrict__ hcur,
        unsigned short* __restrict__ hcur_bf, unsigned char* __restrict__ xq) {
    __shared__ float wl[DIM];
    __shared__ float red[4 * DIM];
    int b = blockIdx.x, t = threadIdx.x;
    wl[t] = watl[t]; wl[t + 256] = watl[t + 256];
    __syncthreads();
    int s = starts[b], e = starts[b + 1];
    int w = t >> 6, lane = t & 63;
    int f0 = lane * 4;
    float acc[8] = {0.f,0.f,0.f,0.f,0.f,0.f,0.f,0.f};

    auto proc = [&](int i, const float4& v0, const float4& v1) {
        acc[0] += v0.x; acc[1] += v0.y; acc[2] += v0.z; acc[3] += v0.w;
        acc[4] += v1.x; acc[5] += v1.y; acc[6] += v1.z; acc[7] += v1.w;
        float dot = v0.x*wl[f0] + v0.y*wl[f0+1] + v0.z*wl[f0+2] + v0.w*wl[f0+3]
                  + v1.x*wl[256+f0] + v1.y*wl[256+f0+1] + v1.z*wl[256+f0+2] + v1.w*wl[256+f0+3];
        #pragma unroll
        for (int off = 32; off > 0; off >>= 1) dot += __shfl_xor(dot, off);
        if (lane == 0) left_att[i] = dot;
        if constexpr (WRITE_XQ) {
            unsigned int q0 = (unsigned int)__builtin_amdgcn_cvt_pk_fp8_f32(v0.x, v0.y, 0, false);
            q0 = (unsigned int)__builtin_amdgcn_cvt_pk_fp8_f32(v0.z, v0.w, (int)q0, true);
            unsigned int q1 = (unsigned int)__builtin_amdgcn_cvt_pk_fp8_f32(v1.x, v1.y, 0, false);
            q1 = (unsigned int)__builtin_amdgcn_cvt_pk_fp8_f32(v1.z, v1.w, (int)q1, true);
            *reinterpret_cast<unsigned int*>(xq + (size_t)i * DIM + f0) = q0;
            *reinterpret_cast<unsigned int*>(xq + (size_t)i * DIM + 256 + f0) = q1;
        }
    };

    int i = s + w;
    for (; i + 4 < e; i += 8) {
        float4 a0 = *reinterpret_cast<const float4*>(x + (size_t)i * DIM + f0);
        float4 a1 = *reinterpret_cast<const float4*>(x + (size_t)i * DIM + 256 + f0);
        float4 b0 = *reinterpret_cast<const float4*>(x + (size_t)(i + 4) * DIM + f0);
        float4 b1 = *reinterpret_cast<const float4*>(x + (size_t)(i + 4) * DIM + 256 + f0);
        proc(i, a0, a1);
        proc(i + 4, b0, b1);
    }
    if (i < e) {
        float4 a0 = *reinterpret_cast<const float4*>(x + (size_t)i * DIM + f0);
        float4 a1 = *reinterpret_cast<const float4*>(x + (size_t)i * DIM + 256 + f0);
        proc(i, a0, a1);
    }

    #pragma unroll
    for (int j = 0; j < 4; j++) {
        red[w * DIM + f0 + j]       = acc[j];
        red[w * DIM + 256 + f0 + j] = acc[4 + j];
    }
    __syncthreads();
    float s0 = red[t]       + red[DIM + t]       + red[2*DIM + t]       + red[3*DIM + t];
    float s1 = red[256 + t] + red[DIM + 256 + t] + red[2*DIM + 256 + t] + red[3*DIM + 256 + t];
    hcur[(size_t)b * DIM + t] = s0;
    hcur[(size_t)b * DIM + 256 + t] = s1;
    hcur_bf[(size_t)b * DIM + t] = f2bf(s0);
    hcur_bf[(size_t)b * DIM + 256 + t] = f2bf(s1);
}

// ---------------- fused attention: right-att dot + segment softmax + weighted sum ----------------
template<bool XQ>
__global__ __launch_bounds__(256) void k_att(const float* __restrict__ x,
        const unsigned char* __restrict__ xq, const float* __restrict__ left,
        const int* __restrict__ starts, const float* __restrict__ hcur,
        const float* __restrict__ watr, unsigned short* __restrict__ swbf) {
    __shared__ float red[4 * DIM];
    __shared__ float rscal[8];
    int b = blockIdx.x, t = threadIdx.x;
    int w = t >> 6, lane = t & 63;

    float p = hcur[(size_t)b * DIM + t] * watr[t] + hcur[(size_t)b * DIM + 256 + t] * watr[256 + t];
    red[t] = p; __syncthreads();
    for (int off = 128; off > 0; off >>= 1) { if (t < off) red[t] += red[t + off]; __syncthreads(); }
    float ra = red[0];
    __syncthreads();

    int s = starts[b], e = starts[b + 1];
    float m = -1e30f;
    for (int i = s + t; i < e; i += 256) {
        float a = left[i] + ra; a = a >= 0.f ? a : 0.01f * a;
        m = fmaxf(m, a);
    }
    red[t] = m; __syncthreads();
    for (int off = 128; off > 0; off >>= 1) { if (t < off) red[t] = fmaxf(red[t], red[t + off]); __syncthreads(); }
    m = red[0];
    __syncthreads();

    float acc[8] = {0.f,0.f,0.f,0.f,0.f,0.f,0.f,0.f};
    float esum = 0.f;
    if constexpr (XQ) {
        int f0 = lane * 8;
        auto qacc = [&](uint2 q, float ev) {
            floatx2 p0 = __builtin_amdgcn_cvt_pk_f32_fp8((int)q.x, false);
            floatx2 p1 = __builtin_amdgcn_cvt_pk_f32_fp8((int)q.x, true);
            floatx2 p2 = __builtin_amdgcn_cvt_pk_f32_fp8((int)q.y, false);
            floatx2 p3 = __builtin_amdgcn_cvt_pk_f32_fp8((int)q.y, true);
            acc[0] += ev * p0[0]; acc[1] += ev * p0[1];
            acc[2] += ev * p1[0]; acc[3] += ev * p1[1];
            acc[4] += ev * p2[0]; acc[5] += ev * p2[1];
            acc[6] += ev * p3[0]; acc[7] += ev * p3[1];
        };
        int i = s + w;
        for (; i + 4 < e; i += 8) {
            uint2 q0 = *reinterpret_cast<const uint2*>(xq + (size_t)i * DIM + f0);
            uint2 q1 = *reinterpret_cast<const uint2*>(xq + (size_t)(i + 4) * DIM + f0);
            float l0 = left[i], l1 = left[i + 4];
            float a0 = l0 + ra; a0 = a0 >= 0.f ? a0 : 0.01f * a0;
            float a1 = l1 + ra; a1 = a1 >= 0.f ? a1 : 0.01f * a1;
            float e0 = __expf(a0 - m), e1 = __expf(a1 - m);
            esum += e0 + e1;
            qacc(q0, e0);
            qacc(q1, e1);
        }
        if (i < e) {
            uint2 q0 = *reinterpret_cast<const uint2*>(xq + (size_t)i * DIM + f0);
            float a0 = left[i] + ra; a0 = a0 >= 0.f ? a0 : 0.01f * a0;
            float e0 = __expf(a0 - m);
            esum += e0;
            qacc(q0, e0);
        }
        #pragma unroll
        for (int j = 0; j < 8; j++) red[w * DIM + f0 + j] = acc[j];
    } else {
        int f0 = lane * 4;
        for (int i = s + w; i < e; i += 4) {
            float a0 = left[i] + ra; a0 = a0 >= 0.f ? a0 : 0.01f * a0;
            float e0 = __expf(a0 - m);
            esum += e0;
            float4 v0 = *reinterpret_cast<const float4*>(x + (size_t)i * DIM + f0);
            float4 v1 = *reinterpret_cast<const float4*>(x + (size_t)i * DIM + 256 + f0);
            acc[0] += e0 * v0.x; acc[1] += e0 * v0.y; acc[2] += e0 * v0.z; acc[3] += e0 * v0.w;
            acc[4] += e0 * v1.x; acc[5] += e0 * v1.y; acc[6] += e0 * v1.z; acc[7] += e0 * v1.w;
        }
        #pragma unroll
        for (int j = 0; j < 4; j++) {
            red[w * DIM + f0 + j]       = acc[j];
            red[w * DIM + 256 + f0 + j] = acc[4 + j];
        }
    }
    #pragma unroll
    for (int off = 32; off > 0; off >>= 1) esum += __shfl_xor(esum, off);
    if (lane == 0) rscal[w] = esum;
    __syncthreads();
    float tot = rscal[0] + rscal[1] + rscal[2] + rscal[3];
    float inv = tot > 0.f ? 1.0f / tot : 0.0f;
    float s0 = (red[t]       + red[DIM + t]       + red[2*DIM + t]       + red[3*DIM + t])       * inv;
    float s1 = (red[256 + t] + red[DIM + 256 + t] + red[2*DIM + 256 + t] + red[3*DIM + 256 + t]) * inv;
    swbf[(size_t)b * DIM + t] = f2bf(s0);
    swbf[(size_t)b * DIM + 256 + t] = f2bf(s1);
}

// ---------------- bf16 MFMA GEMM, 2-phase global_load_lds pipeline (R2 verbatim) ----------------
template<bool ELU_BF>
__global__ __launch_bounds__(256, 2) void k_gemm(const unsigned short* __restrict__ A0,
        const unsigned short* __restrict__ A1, const unsigned short* __restrict__ Wt0,
        const unsigned short* __restrict__ Wt1, float* __restrict__ Cf0,
        float* __restrict__ Cf1, unsigned short* __restrict__ Cbf, int Ncols) {
    __shared__ __align__(16) unsigned short lA[2][128 * 64];
    __shared__ __align__(16) unsigned short lW[2][128 * 64];
    const unsigned short* A  = (blockIdx.z == 0) ? A0  : A1;
    const unsigned short* Wt = (blockIdx.z == 0) ? Wt0 : Wt1;
    float* Cf = (blockIdx.z == 0) ? Cf0 : Cf1;

    int t = threadIdx.x;
    int w = t >> 6, lane = t & 63;
    int wr = w >> 1, wc = w & 1;
    int mbase = blockIdx.x * 128;
    int nbase = blockIdx.y * 128;
    int fr = lane & 15, hi = lane >> 4;
    int swz_r = (fr & 7) << 4;

    int rbase = t >> 3;
    int cole = ((((t & 7) * 16) ^ ((rbase & 7) << 4)) >> 1);
    int ldsoff = t * 16;

    floatx4 acc[4][4];
    #pragma unroll
    for (int m = 0; m < 4; m++)
        #pragma unroll
        for (int n = 0; n < 4; n++) {
            acc[m][n][0] = 0.f; acc[m][n][1] = 0.f; acc[m][n][2] = 0.f; acc[m][n][3] = 0.f;
        }

    const unsigned short* gA = A  + (size_t)(mbase + rbase) * DIM + cole;
    const unsigned short* gW = Wt + (size_t)(nbase + rbase) * DIM + cole;

    auto stage = [&](int kk, int buf) {
        #pragma unroll
        for (int c = 0; c < 4; ++c) {
            gload_lds16(gA + (size_t)(c * 32) * DIM + kk, (char*)&lA[buf][0] + c * 4096 + ldsoff);
            gload_lds16(gW + (size_t)(c * 32) * DIM + kk, (char*)&lW[buf][0] + c * 4096 + ldsoff);
        }
    };

    stage(0, 0);
    __syncthreads();
    int cur = 0;
    for (int it = 0; it < 8; ++it) {
        if (it < 7) stage((it + 1) * 64, cur ^ 1);
        #pragma unroll
        for (int ks = 0; ks < 2; ++ks) {
            short8 af[4], bf[4];
            int bc = (ks * 64 + hi * 16) ^ swz_r;
            #pragma unroll
            for (int m = 0; m < 4; ++m) {
                int row = wr * 64 + m * 16 + fr;
                af[m] = *reinterpret_cast<const short8*>(&lA[cur][(row * 128 + bc) >> 1]);
            }
            #pragma unroll
            for (int n = 0; n < 4; ++n) {
                int row = wc * 64 + n * 16 + fr;
                bf[n] = *reinterpret_cast<const short8*>(&lW[cur][(row * 128 + bc) >> 1]);
            }
            #pragma unroll
            for (int m = 0; m < 4; ++m)
                #pragma unroll
                for (int n = 0; n < 4; ++n)
                    acc[m][n] = __builtin_amdgcn_mfma_f32_16x16x32_bf16(af[m], bf[n], acc[m][n], 0, 0, 0);
        }
        if (it < 7) __syncthreads();
        cur ^= 1;
    }

    int rq = hi * 4;
    #pragma unroll
    for (int m = 0; m < 4; m++) {
        #pragma unroll
        for (int n = 0; n < 4; n++) {
            int col = nbase + wc * 64 + n * 16 + fr;
            #pragma unroll
            for (int r = 0; r < 4; r++) {
                int row = mbase + wr * 64 + m * 16 + rq + r;
                float v = acc[m][n][r];
                if constexpr (ELU_BF) {
                    v = v > 0.f ? v : (__expf(v) - 1.0f);
                    Cbf[(size_t)row * Ncols + col] = f2bf(v);
                } else {
                    Cf[(size_t)row * Ncols + col] = v;
                }
            }
        }
    }
}

// ---------------- GRU gates + silu ----------------
__global__ __launch_bounds__(256) void k_gate(const float* __restrict__ gi,
        const float* __restrict__ gh, const float* __restrict__ bih,
        const float* __restrict__ bhh, float* __restrict__ hcur,
        unsigned short* __restrict__ hcur_bf) {
    int idx = blockIdx.x * 256 + threadIdx.x;
    int b = idx >> 9, j = idx & 511;
    size_t gb = (size_t)b * HID3;
    float gir = gi[gb + j]        + bih[j];
    float giz = gi[gb + 512 + j]  + bih[512 + j];
    float gin = gi[gb + 1024 + j] + bih[1024 + j];
    float ghr = gh[gb + j]        + bhh[j];
    float ghz = gh[gb + 512 + j]  + bhh[512 + j];
    float ghn = gh[gb + 1024 + j] + bhh[1024 + j];
    float r = 1.0f / (1.0f + __expf(-(gir + ghr)));
    float z = 1.0f / (1.0f + __expf(-(giz + ghz)));
    float n = tanhf(gin + r * ghn);
    float h = hcur[(size_t)b * DIM + j];
    float nh = (1.0f - z) * n + z * h;
    float out = nh / (1.0f + __expf(-nh));
    hcur[(size_t)b * DIM + j] = out;
    hcur_bf[(size_t)b * DIM + j] = f2bf(out);
}

// ---------------- final linear ----------------
__global__ __launch_bounds__(128) void k_fin(const float* __restrict__ hcur,
        const float* __restrict__ Wlin, const float* __restrict__ blin,
        float* __restrict__ out) {
    __shared__ float rows[16 * DIM];
    int t = threadIdx.x;
    int b0 = blockIdx.x * 16;
    for (int i = t; i < 16 * DIM / 4; i += 128)
        reinterpret_cast<float4*>(rows)[i] = reinterpret_cast<const float4*>(hcur + (size_t)b0 * DIM)[i];
    __syncthreads();
    float acc[16];
    #pragma unroll
    for (int r = 0; r < 16; r++) acc[r] = 0.f;
    #pragma unroll 4
    for (int k = 0; k < DIM; k++) {
        float wv = Wlin[k * OUTD + t];
        #pragma unroll
        for (int r = 0; r < 16; r++) acc[r] += rows[r * DIM + k] * wv;
    }
    float bl = blin[t];
    #pragma unroll
    for (int r = 0; r < 16; r++) out[(size_t)(b0 + r) * OUTD + t] = acc[r] + bl;
}

extern "C" void kernel_launch(void* const* d_in, const int* in_sizes, int n_in,
                              void* d_out, int out_size, void* d_ws, size_t ws_size,
                              hipStream_t stream) {
    const float* x     = (const float*)d_in[0];
    const int*   seg   = (const int*)d_in[1];
    const float* watl  = (const float*)d_in[2];
    const float* watr  = (const float*)d_in[3];
    const float* Wnode = (const float*)d_in[4];
    const float* Wih   = (const float*)d_in[5];
    const float* Whh   = (const float*)d_in[6];
    const float* bih   = (const float*)d_in[7];
    const float* bhh   = (const float*)d_in[8];
    const float* Wlin  = (const float*)d_in[9];
    const float* blin  = (const float*)d_in[10];
    float* out = (float*)d_out;

    char* ws = (char*)d_ws;
    size_t off = 0;
    auto alloc = [&](size_t bytes) -> void* {
        void* p = ws + off;
        off += bytes;
        off = (off + 255) & ~(size_t)255;
        return p;
    };
    float*          left    = (float*)          alloc((size_t)N_NODES * sizeof(float));
    float*          hcur    = (float*)          alloc((size_t)NGRAPH * DIM * sizeof(float));
    unsigned short* hcurbf  = (unsigned short*) alloc((size_t)NGRAPH * DIM * 2);
    unsigned short* hgbf    = (unsigned short*) alloc((size_t)NGRAPH * DIM * 2);
    unsigned short* swbf    = (unsigned short*) alloc((size_t)NGRAPH * DIM * 2);
    float*          gi      = (float*)          alloc((size_t)NGRAPH * HID3 * sizeof(float));
    float*          gh      = (float*)          alloc((size_t)NGRAPH * HID3 * sizeof(float));
    unsigned short* WnT     = (unsigned short*) alloc((size_t)DIM * DIM * 2);
    unsigned short* Wihb    = (unsigned short*) alloc((size_t)HID3 * DIM * 2);
    unsigned short* Whhb    = (unsigned short*) alloc((size_t)HID3 * DIM * 2);
    unsigned char*  xq      = (unsigned char*)(ws + off);
    bool use_xq = (off + (size_t)N_NODES * DIM) <= ws_size;

    k_prep<<<6409, 256, 0, stream>>>(Wih, Whh, Wnode, seg, Wihb, Whhb, WnT,
                                     (int*)alloc(0));  // starts placed after xq guard below

    // starts buffer: allocate explicitly (needed regardless of xq)
    // NOTE: alloc(0) above returned current offset without consuming; reserve now.
    int* starts = (int*)alloc((NGRAPH + 1) * sizeof(int));
    // re-point xq past starts
    xq = (unsigned char*)(ws + off);
    use_xq = (off + (size_t)N_NODES * DIM) <= ws_size;

    if (use_xq)
        k_init<true ><<<NGRAPH, 256, 0, stream>>>(x, starts, watl, left, hcur, hcurbf, xq);
    else
        k_init<false><<<NGRAPH, 256, 0, stream>>>(x, starts, watl, left, hcur, hcurbf, nullptr);

    for (int ts = 0; ts < 2; ts++) {
        if (use_xq)
            k_att<true ><<<NGRAPH, 256, 0, stream>>>(x, xq, left, starts, hcur, watr, swbf);
        else
            k_att<false><<<NGRAPH, 256, 0, stream>>>(x, xq, left, starts, hcur, watr, swbf);
        k_gemm<true ><<<dim3(NGRAPH / 128, DIM / 128, 1), 256, 0, stream>>>(
            swbf, nullptr, WnT, nullptr, nullptr, nullptr, hgbf, DIM);
        k_gemm<false><<<dim3(NGRAPH / 128, HID3 / 128, 2), 256, 0, stream>>>(
            hgbf, hcurbf, Wihb, Whhb, gi, gh, nullptr, HID3);
        k_gate<<<(NGRAPH * DIM) / 256, 256, 0, stream>>>(gi, gh, bih, bhh, hcur, hcurbf);
    }
    k_fin<<<NGRAPH / 16, 128, 0, stream>>>(hcur, Wlin, blin, out);
}

// Round 6
// 301.429 us; speedup vs baseline: 3.4743x; 1.1593x over previous
//
#include <hip/hip_runtime.h>
#include <hip/hip_bf16.h>
#include <cstdint>
#include <cstddef>

#define N_NODES 262144
#define NGRAPH  2048
#define DIM     512
#define HID3    1536
#define OUTD    128

typedef __attribute__((ext_vector_type(8))) short  short8;
typedef __attribute__((ext_vector_type(4))) float  floatx4;
typedef __attribute__((ext_vector_type(2))) float  floatx2;

__device__ inline unsigned short f2bf(float f) {
    union { float f; uint32_t u; } v; v.f = f;
    uint32_t u = v.u;
    return (unsigned short)((u + 0x7fffu + ((u >> 16) & 1u)) >> 16);
}
__device__ inline float bf2f(unsigned short h) {
    union { uint32_t u; float f; } v; v.u = ((uint32_t)h) << 16; return v.f;
}

__device__ __forceinline__ void gload_lds16(const void* g, void* l) {
    __builtin_amdgcn_global_load_lds((const __attribute__((address_space(1))) void*)g,
                                     (__attribute__((address_space(3))) void*)l, 16, 0, 0);
}

// ---------------- prep: weight converts + transpose + graph starts ----------------
__global__ __launch_bounds__(256) void k_prep(const float* __restrict__ Wih,
        const float* __restrict__ Whh, const float* __restrict__ Wnode,
        const int* __restrict__ seg, unsigned short* __restrict__ Wihb,
        unsigned short* __restrict__ Whhb, unsigned short* __restrict__ WnT,
        int* __restrict__ starts) {
    __shared__ float tile[32][33];
    int id = blockIdx.x, t = threadIdx.x;
    if (id < 3072) {
        int i = id * 256 + t; Wihb[i] = f2bf(Wih[i]);
    } else if (id < 6144) {
        int i = (id - 3072) * 256 + t; Whhb[i] = f2bf(Whh[i]);
    } else if (id < 6400) {
        int idx = id - 6144;
        int bx = idx >> 4, by = idx & 15;
        int tx = t & 31, ty = t >> 5;
        for (int r = 0; r < 32; r += 8)
            tile[ty + r][tx] = Wnode[(size_t)(bx * 32 + ty + r) * DIM + by * 32 + tx];
        __syncthreads();
        for (int r = 0; r < 32; r += 8)
            WnT[(size_t)(by * 32 + ty + r) * DIM + bx * 32 + tx] = f2bf(tile[tx][ty + r]);
    } else {
        int b = (id - 6400) * 256 + t;
        if (b <= NGRAPH) {
            int lo = 0, hi = N_NODES;
            while (lo < hi) { int mid = (lo + hi) >> 1; if (seg[mid] < b) lo = mid + 1; else hi = mid; }
            starts[b] = lo;
        }
    }
}

// ---------------- init: sum-pool h0, left_att, x->fp8 cache (nt loads on x) ----------------
template<bool WRITE_XQ>
__global__ __launch_bounds__(256) void k_init(const float* __restrict__ x,
        const int* __restrict__ starts, const float* __restrict__ watl,
        float* __restrict__ left_att, float* __restrict__ hcur,
        unsigned short* __restrict__ hcur_bf, unsigned char* __restrict__ xq) {
    __shared__ float wl[DIM];
    __shared__ float red[4 * DIM];
    int b = blockIdx.x, t = threadIdx.x;
    wl[t] = watl[t]; wl[t + 256] = watl[t + 256];
    __syncthreads();
    int s = starts[b], e = starts[b + 1];
    int w = t >> 6, lane = t & 63;
    int f0 = lane * 4;
    float acc[8] = {0.f,0.f,0.f,0.f,0.f,0.f,0.f,0.f};

    auto proc = [&](int i, floatx4 v0, floatx4 v1) {
        acc[0] += v0[0]; acc[1] += v0[1]; acc[2] += v0[2]; acc[3] += v0[3];
        acc[4] += v1[0]; acc[5] += v1[1]; acc[6] += v1[2]; acc[7] += v1[3];
        float dot = v0[0]*wl[f0] + v0[1]*wl[f0+1] + v0[2]*wl[f0+2] + v0[3]*wl[f0+3]
                  + v1[0]*wl[256+f0] + v1[1]*wl[256+f0+1] + v1[2]*wl[256+f0+2] + v1[3]*wl[256+f0+3];
        #pragma unroll
        for (int off = 32; off > 0; off >>= 1) dot += __shfl_xor(dot, off);
        if (lane == 0) left_att[i] = dot;
        if constexpr (WRITE_XQ) {
            unsigned int q0 = (unsigned int)__builtin_amdgcn_cvt_pk_fp8_f32(v0[0], v0[1], 0, false);
            q0 = (unsigned int)__builtin_amdgcn_cvt_pk_fp8_f32(v0[2], v0[3], (int)q0, true);
            unsigned int q1 = (unsigned int)__builtin_amdgcn_cvt_pk_fp8_f32(v1[0], v1[1], 0, false);
            q1 = (unsigned int)__builtin_amdgcn_cvt_pk_fp8_f32(v1[2], v1[3], (int)q1, true);
            *reinterpret_cast<unsigned int*>(xq + (size_t)i * DIM + f0) = q0;
            *reinterpret_cast<unsigned int*>(xq + (size_t)i * DIM + 256 + f0) = q1;
        }
    };

    int i = s + w;
    for (; i + 4 < e; i += 8) {
        floatx4 a0 = __builtin_nontemporal_load(reinterpret_cast<const floatx4*>(x + (size_t)i * DIM + f0));
        floatx4 a1 = __builtin_nontemporal_load(reinterpret_cast<const floatx4*>(x + (size_t)i * DIM + 256 + f0));
        floatx4 b0 = __builtin_nontemporal_load(reinterpret_cast<const floatx4*>(x + (size_t)(i + 4) * DIM + f0));
        floatx4 b1 = __builtin_nontemporal_load(reinterpret_cast<const floatx4*>(x + (size_t)(i + 4) * DIM + 256 + f0));
        proc(i, a0, a1);
        proc(i + 4, b0, b1);
    }
    if (i < e) {
        floatx4 a0 = __builtin_nontemporal_load(reinterpret_cast<const floatx4*>(x + (size_t)i * DIM + f0));
        floatx4 a1 = __builtin_nontemporal_load(reinterpret_cast<const floatx4*>(x + (size_t)i * DIM + 256 + f0));
        proc(i, a0, a1);
    }

    #pragma unroll
    for (int j = 0; j < 4; j++) {
        red[w * DIM + f0 + j]       = acc[j];
        red[w * DIM + 256 + f0 + j] = acc[4 + j];
    }
    __syncthreads();
    float s0 = red[t]       + red[DIM + t]       + red[2*DIM + t]       + red[3*DIM + t];
    float s1 = red[256 + t] + red[DIM + 256 + t] + red[2*DIM + 256 + t] + red[3*DIM + 256 + t];
    hcur[(size_t)b * DIM + t] = s0;
    hcur[(size_t)b * DIM + 256 + t] = s1;
    hcur_bf[(size_t)b * DIM + t] = f2bf(s0);
    hcur_bf[(size_t)b * DIM + 256 + t] = f2bf(s1);
}

// ---------------- fused attention: shfl reductions, fp8 cache reads ----------------
template<bool XQ>
__global__ __launch_bounds__(256) void k_att(const float* __restrict__ x,
        const unsigned char* __restrict__ xq, const float* __restrict__ left,
        const int* __restrict__ starts, const float* __restrict__ hcur,
        const float* __restrict__ watr, unsigned short* __restrict__ swbf) {
    __shared__ float red[4 * DIM];
    __shared__ float rsh[4];
    __shared__ float rsm[4];
    __shared__ float rscal[4];
    int b = blockIdx.x, t = threadIdx.x;
    int w = t >> 6, lane = t & 63;

    // right_att = dot(hcur[b], watr): wave shfl + 4-way LDS combine
    float p = hcur[(size_t)b * DIM + t] * watr[t] + hcur[(size_t)b * DIM + 256 + t] * watr[256 + t];
    #pragma unroll
    for (int off = 32; off > 0; off >>= 1) p += __shfl_xor(p, off);
    if (lane == 0) rsh[w] = p;
    int s = starts[b], e = starts[b + 1];
    __syncthreads();
    float ra = rsh[0] + rsh[1] + rsh[2] + rsh[3];

    // segment max of leaky_relu(left + ra)
    float m = -1e30f;
    for (int i = s + t; i < e; i += 256) {
        float a = left[i] + ra; a = a >= 0.f ? a : 0.01f * a;
        m = fmaxf(m, a);
    }
    #pragma unroll
    for (int off = 32; off > 0; off >>= 1) m = fmaxf(m, __shfl_xor(m, off));
    if (lane == 0) rsm[w] = m;
    __syncthreads();
    m = fmaxf(fmaxf(rsm[0], rsm[1]), fmaxf(rsm[2], rsm[3]));

    float acc[8] = {0.f,0.f,0.f,0.f,0.f,0.f,0.f,0.f};
    float esum = 0.f;
    if constexpr (XQ) {
        int f0 = lane * 8;
        auto qacc = [&](uint2 q, float ev) {
            floatx2 p0 = __builtin_amdgcn_cvt_pk_f32_fp8((int)q.x, false);
            floatx2 p1 = __builtin_amdgcn_cvt_pk_f32_fp8((int)q.x, true);
            floatx2 p2 = __builtin_amdgcn_cvt_pk_f32_fp8((int)q.y, false);
            floatx2 p3 = __builtin_amdgcn_cvt_pk_f32_fp8((int)q.y, true);
            acc[0] += ev * p0[0]; acc[1] += ev * p0[1];
            acc[2] += ev * p1[0]; acc[3] += ev * p1[1];
            acc[4] += ev * p2[0]; acc[5] += ev * p2[1];
            acc[6] += ev * p3[0]; acc[7] += ev * p3[1];
        };
        int i = s + w;
        for (; i + 4 < e; i += 8) {
            uint2 q0 = *reinterpret_cast<const uint2*>(xq + (size_t)i * DIM + f0);
            uint2 q1 = *reinterpret_cast<const uint2*>(xq + (size_t)(i + 4) * DIM + f0);
            float a0 = left[i] + ra;     a0 = a0 >= 0.f ? a0 : 0.01f * a0;
            float a1 = left[i + 4] + ra; a1 = a1 >= 0.f ? a1 : 0.01f * a1;
            float e0 = __expf(a0 - m), e1 = __expf(a1 - m);
            esum += e0 + e1;
            qacc(q0, e0);
            qacc(q1, e1);
        }
        if (i < e) {
            uint2 q0 = *reinterpret_cast<const uint2*>(xq + (size_t)i * DIM + f0);
            float a0 = left[i] + ra; a0 = a0 >= 0.f ? a0 : 0.01f * a0;
            float e0 = __expf(a0 - m);
            esum += e0;
            qacc(q0, e0);
        }
        #pragma unroll
        for (int j = 0; j < 8; j++) red[w * DIM + f0 + j] = acc[j];
    } else {
        int f0 = lane * 4;
        for (int i = s + w; i < e; i += 4) {
            float a0 = left[i] + ra; a0 = a0 >= 0.f ? a0 : 0.01f * a0;
            float e0 = __expf(a0 - m);
            esum += e0;
            float4 v0 = *reinterpret_cast<const float4*>(x + (size_t)i * DIM + f0);
            float4 v1 = *reinterpret_cast<const float4*>(x + (size_t)i * DIM + 256 + f0);
            acc[0] += e0 * v0.x; acc[1] += e0 * v0.y; acc[2] += e0 * v0.z; acc[3] += e0 * v0.w;
            acc[4] += e0 * v1.x; acc[5] += e0 * v1.y; acc[6] += e0 * v1.z; acc[7] += e0 * v1.w;
        }
        #pragma unroll
        for (int j = 0; j < 4; j++) {
            red[w * DIM + f0 + j]       = acc[j];
            red[w * DIM + 256 + f0 + j] = acc[4 + j];
        }
    }
    #pragma unroll
    for (int off = 32; off > 0; off >>= 1) esum += __shfl_xor(esum, off);
    if (lane == 0) rscal[w] = esum;
    __syncthreads();
    float tot = rscal[0] + rscal[1] + rscal[2] + rscal[3];
    float inv = tot > 0.f ? 1.0f / tot : 0.0f;
    float s0 = (red[t]       + red[DIM + t]       + red[2*DIM + t]       + red[3*DIM + t])       * inv;
    float s1 = (red[256 + t] + red[DIM + 256 + t] + red[2*DIM + 256 + t] + red[3*DIM + 256 + t]) * inv;
    swbf[(size_t)b * DIM + t] = f2bf(s0);
    swbf[(size_t)b * DIM + 256 + t] = f2bf(s1);
}

// ---------------- bf16 MFMA GEMM, 2-phase pipeline, dual-problem z-select ----------------
// All A matrices are [M x 512] (K=512 row length). Per-z: A, Wt, output (fp32 or elu->bf16),
// Ncols, and y-extent (blocks with by >= ny exit).
__global__ __launch_bounds__(256, 2) void k_gemm(const unsigned short* __restrict__ A0,
        const unsigned short* __restrict__ Wt0, float* __restrict__ Cf0,
        unsigned short* __restrict__ Cb0, int Ncols0, int ny0,
        const unsigned short* __restrict__ A1, const unsigned short* __restrict__ Wt1,
        float* __restrict__ Cf1, unsigned short* __restrict__ Cb1, int Ncols1) {
    const int z = blockIdx.z;
    if (z == 0 && (int)blockIdx.y >= ny0) return;
    const unsigned short* A  = z ? A1  : A0;
    const unsigned short* Wt = z ? Wt1 : Wt0;
    float* Cf          = z ? Cf1 : Cf0;
    unsigned short* Cb = z ? Cb1 : Cb0;
    const int Ncols    = z ? Ncols1 : Ncols0;

    __shared__ __align__(16) unsigned short lA[2][128 * 64];
    __shared__ __align__(16) unsigned short lW[2][128 * 64];

    int t = threadIdx.x;
    int w = t >> 6, lane = t & 63;
    int wr = w >> 1, wc = w & 1;
    int mbase = blockIdx.x * 128;
    int nbase = blockIdx.y * 128;
    int fr = lane & 15, hi = lane >> 4;
    int swz_r = (fr & 7) << 4;

    int rbase = t >> 3;
    int cole = ((((t & 7) * 16) ^ ((rbase & 7) << 4)) >> 1);
    int ldsoff = t * 16;

    floatx4 acc[4][4];
    #pragma unroll
    for (int m = 0; m < 4; m++)
        #pragma unroll
        for (int n = 0; n < 4; n++) {
            acc[m][n][0] = 0.f; acc[m][n][1] = 0.f; acc[m][n][2] = 0.f; acc[m][n][3] = 0.f;
        }

    const unsigned short* gA = A  + (size_t)(mbase + rbase) * DIM + cole;
    const unsigned short* gW = Wt + (size_t)(nbase + rbase) * DIM + cole;

    auto stage = [&](int kk, int buf) {
        #pragma unroll
        for (int c = 0; c < 4; ++c) {
            gload_lds16(gA + (size_t)(c * 32) * DIM + kk, (char*)&lA[buf][0] + c * 4096 + ldsoff);
            gload_lds16(gW + (size_t)(c * 32) * DIM + kk, (char*)&lW[buf][0] + c * 4096 + ldsoff);
        }
    };

    stage(0, 0);
    __syncthreads();
    int cur = 0;
    for (int it = 0; it < 8; ++it) {
        if (it < 7) stage((it + 1) * 64, cur ^ 1);
        #pragma unroll
        for (int ks = 0; ks < 2; ++ks) {
            short8 af[4], bf[4];
            int bc = (ks * 64 + hi * 16) ^ swz_r;
            #pragma unroll
            for (int m = 0; m < 4; ++m) {
                int row = wr * 64 + m * 16 + fr;
                af[m] = *reinterpret_cast<const short8*>(&lA[cur][(row * 128 + bc) >> 1]);
            }
            #pragma unroll
            for (int n = 0; n < 4; ++n) {
                int row = wc * 64 + n * 16 + fr;
                bf[n] = *reinterpret_cast<const short8*>(&lW[cur][(row * 128 + bc) >> 1]);
            }
            #pragma unroll
            for (int m = 0; m < 4; ++m)
                #pragma unroll
                for (int n = 0; n < 4; ++n)
                    acc[m][n] = __builtin_amdgcn_mfma_f32_16x16x32_bf16(af[m], bf[n], acc[m][n], 0, 0, 0);
        }
        if (it < 7) __syncthreads();
        cur ^= 1;
    }

    int rq = hi * 4;
    #pragma unroll
    for (int m = 0; m < 4; m++) {
        #pragma unroll
        for (int n = 0; n < 4; n++) {
            int col = nbase + wc * 64 + n * 16 + fr;
            #pragma unroll
            for (int r = 0; r < 4; r++) {
                int row = mbase + wr * 64 + m * 16 + rq + r;
                float v = acc[m][n][r];
                if (Cb) {
                    v = v > 0.f ? v : (__expf(v) - 1.0f);
                    Cb[(size_t)row * Ncols + col] = f2bf(v);
                } else {
                    Cf[(size_t)row * Ncols + col] = v;
                }
            }
        }
    }
}

// ---------------- GRU gates + silu (float4 vectorized) ----------------
__global__ __launch_bounds__(256) void k_gate(const float* __restrict__ gi,
        const float* __restrict__ gh, const float* __restrict__ bih,
        const float* __restrict__ bhh, float* __restrict__ hcur,
        unsigned short* __restrict__ hcur_bf) {
    int idx = blockIdx.x * 256 + threadIdx.x;   // over NGRAPH*128
    int b = idx >> 7, j = (idx & 127) << 2;
    size_t gb = (size_t)b * HID3;
    floatx4 gir = *reinterpret_cast<const floatx4*>(gi + gb + j);
    floatx4 giz = *reinterpret_cast<const floatx4*>(gi + gb + 512 + j);
    floatx4 gin = *reinterpret_cast<const floatx4*>(gi + gb + 1024 + j);
    floatx4 ghr = *reinterpret_cast<const floatx4*>(gh + gb + j);
    floatx4 ghz = *reinterpret_cast<const floatx4*>(gh + gb + 512 + j);
    floatx4 ghn = *reinterpret_cast<const floatx4*>(gh + gb + 1024 + j);
    floatx4 bir = *reinterpret_cast<const floatx4*>(bih + j);
    floatx4 biz = *reinterpret_cast<const floatx4*>(bih + 512 + j);
    floatx4 bin = *reinterpret_cast<const floatx4*>(bih + 1024 + j);
    floatx4 bhr = *reinterpret_cast<const floatx4*>(bhh + j);
    floatx4 bhz = *reinterpret_cast<const floatx4*>(bhh + 512 + j);
    floatx4 bhn = *reinterpret_cast<const floatx4*>(bhh + 1024 + j);
    floatx4 hp  = *reinterpret_cast<const floatx4*>(hcur + (size_t)b * DIM + j);
    floatx4 ov;
    ushort4 ob;
    #pragma unroll
    for (int r = 0; r < 4; r++) {
        float rg = 1.0f / (1.0f + __expf(-(gir[r] + bir[r] + ghr[r] + bhr[r])));
        float zg = 1.0f / (1.0f + __expf(-(giz[r] + biz[r] + ghz[r] + bhz[r])));
        float nn = tanhf(gin[r] + bin[r] + rg * (ghn[r] + bhn[r]));
        float nh = (1.0f - zg) * nn + zg * hp[r];
        float o = nh / (1.0f + __expf(-nh));
        ov[r] = o;
        reinterpret_cast<unsigned short*>(&ob)[r] = f2bf(o);
    }
    *reinterpret_cast<floatx4*>(hcur + (size_t)b * DIM + j) = ov;
    *reinterpret_cast<ushort4*>(hcur_bf + (size_t)b * DIM + j) = ob;
}

// ---------------- final linear ----------------
__global__ __launch_bounds__(128) void k_fin(const float* __restrict__ hcur,
        const float* __restrict__ Wlin, const float* __restrict__ blin,
        float* __restrict__ out) {
    __shared__ float rows[16 * DIM];
    int t = threadIdx.x;
    int b0 = blockIdx.x * 16;
    for (int i = t; i < 16 * DIM / 4; i += 128)
        reinterpret_cast<float4*>(rows)[i] = reinterpret_cast<const float4*>(hcur + (size_t)b0 * DIM)[i];
    __syncthreads();
    float acc[16];
    #pragma unroll
    for (int r = 0; r < 16; r++) acc[r] = 0.f;
    #pragma unroll 4
    for (int k = 0; k < DIM; k++) {
        float wv = Wlin[k * OUTD + t];
        #pragma unroll
        for (int r = 0; r < 16; r++) acc[r] += rows[r * DIM + k] * wv;
    }
    float bl = blin[t];
    #pragma unroll
    for (int r = 0; r < 16; r++) out[(size_t)(b0 + r) * OUTD + t] = acc[r] + bl;
}

extern "C" void kernel_launch(void* const* d_in, const int* in_sizes, int n_in,
                              void* d_out, int out_size, void* d_ws, size_t ws_size,
                              hipStream_t stream) {
    const float* x     = (const float*)d_in[0];
    const int*   seg   = (const int*)d_in[1];
    const float* watl  = (const float*)d_in[2];
    const float* watr  = (const float*)d_in[3];
    const float* Wnode = (const float*)d_in[4];
    const float* Wih   = (const float*)d_in[5];
    const float* Whh   = (const float*)d_in[6];
    const float* bih   = (const float*)d_in[7];
    const float* bhh   = (const float*)d_in[8];
    const float* Wlin  = (const float*)d_in[9];
    const float* blin  = (const float*)d_in[10];
    float* out = (float*)d_out;

    char* ws = (char*)d_ws;
    size_t off = 0;
    auto alloc = [&](size_t bytes) -> void* {
        void* p = ws + off;
        off += bytes;
        off = (off + 255) & ~(size_t)255;
        return p;
    };
    float*          left    = (float*)          alloc((size_t)N_NODES * sizeof(float));
    float*          hcur    = (float*)          alloc((size_t)NGRAPH * DIM * sizeof(float));
    unsigned short* hcurbf  = (unsigned short*) alloc((size_t)NGRAPH * DIM * 2);
    unsigned short* hgbf    = (unsigned short*) alloc((size_t)NGRAPH * DIM * 2);
    unsigned short* swbf    = (unsigned short*) alloc((size_t)NGRAPH * DIM * 2);
    float*          gi      = (float*)          alloc((size_t)NGRAPH * HID3 * sizeof(float));
    float*          gh      = (float*)          alloc((size_t)NGRAPH * HID3 * sizeof(float));
    unsigned short* WnT     = (unsigned short*) alloc((size_t)DIM * DIM * 2);
    unsigned short* Wihb    = (unsigned short*) alloc((size_t)HID3 * DIM * 2);
    unsigned short* Whhb    = (unsigned short*) alloc((size_t)HID3 * DIM * 2);
    int*            starts  = (int*)            alloc((NGRAPH + 1) * sizeof(int));
    unsigned char*  xq      = (unsigned char*)(ws + off);
    bool use_xq = (off + (size_t)N_NODES * DIM) <= ws_size;

    k_prep<<<6409, 256, 0, stream>>>(Wih, Whh, Wnode, seg, Wihb, Whhb, WnT, starts);

    if (use_xq)
        k_init<true ><<<NGRAPH, 256, 0, stream>>>(x, starts, watl, left, hcur, hcurbf, xq);
    else
        k_init<false><<<NGRAPH, 256, 0, stream>>>(x, starts, watl, left, hcur, hcurbf, nullptr);

    for (int ts = 0; ts < 2; ts++) {
        if (use_xq)
            k_att<true ><<<NGRAPH, 256, 0, stream>>>(x, xq, left, starts, hcur, watr, swbf);
        else
            k_att<false><<<NGRAPH, 256, 0, stream>>>(x, xq, left, starts, hcur, watr, swbf);
        // launch A: z=0 -> hg = elu(sw @ WnT^T) [64 blocks], z=1 -> gh = h @ Whh^T [192 blocks]
        k_gemm<<<dim3(NGRAPH / 128, HID3 / 128, 2), 256, 0, stream>>>(
            swbf, WnT, nullptr, hgbf, DIM, DIM / 128,
            hcurbf, Whhb, gh, nullptr, HID3);
        // launch B: gi = hg @ Wih^T [192 blocks]
        k_gemm<<<dim3(NGRAPH / 128, HID3 / 128, 1), 256, 0, stream>>>(
            hgbf, Wihb, gi, nullptr, HID3, HID3 / 128,
            nullptr, nullptr, nullptr, nullptr, 0);
        k_gate<<<(NGRAPH * 128) / 256, 256, 0, stream>>>(gi, gh, bih, bhh, hcur, hcurbf);
    }
    k_fin<<<NGRAPH / 16, 128, 0, stream>>>(hcur, Wlin, blin, out);
}

// Round 7
// 300.889 us; speedup vs baseline: 3.4806x; 1.0018x over previous
//
#include <hip/hip_runtime.h>
#include <hip/hip_bf16.h>
#include <cstdint>
#include <cstddef>

#define N_NODES 262144
#define NGRAPH  2048
#define DIM     512
#define HID3    1536
#define OUTD    128

typedef __attribute__((ext_vector_type(8))) short  short8;
typedef __attribute__((ext_vector_type(4))) float  floatx4;
typedef __attribute__((ext_vector_type(2))) float  floatx2;

__device__ inline unsigned short f2bf(float f) {
    union { float f; uint32_t u; } v; v.f = f;
    uint32_t u = v.u;
    return (unsigned short)((u + 0x7fffu + ((u >> 16) & 1u)) >> 16);
}
__device__ inline float bf2f(unsigned short h) {
    union { uint32_t u; float f; } v; v.u = ((uint32_t)h) << 16; return v.f;
}

__device__ __forceinline__ void gload_lds16(const void* g, void* l) {
    __builtin_amdgcn_global_load_lds((const __attribute__((address_space(1))) void*)g,
                                     (__attribute__((address_space(3))) void*)l, 16, 0, 0);
}

__device__ __forceinline__ int lbound(const int* __restrict__ seg, int b) {
    int lo = 0, hi = N_NODES;
    while (lo < hi) { int mid = (lo + hi) >> 1; if (seg[mid] < b) lo = mid + 1; else hi = mid; }
    return lo;
}

// ============ K1: init (sum-pool h0, left_att, x->fp8, starts) + weight prep ============
// blocks [0,2048): per-graph init (self-lbound, writes starts[b])
// [2048,2816): Wih->bf16 | [2816,3584): Whh->bf16 | [3584,3840): WnT transpose
template<bool WRITE_XQ>
__global__ __launch_bounds__(256) void k_init(const float* __restrict__ x,
        const int* __restrict__ seg, const float* __restrict__ watl,
        const float* __restrict__ Wih, const float* __restrict__ Whh,
        const float* __restrict__ Wnode,
        float* __restrict__ left_att, float* __restrict__ hcur,
        unsigned short* __restrict__ hcur_bf, unsigned char* __restrict__ xq,
        unsigned short* __restrict__ Wihb, unsigned short* __restrict__ Whhb,
        unsigned short* __restrict__ WnT, int* __restrict__ starts) {
    int t = threadIdx.x;
    int bid = blockIdx.x;

    if (bid >= 3584) {            // ---- WnT transpose (256 tile-blocks) ----
        __shared__ float tile[32][33];
        int idx = bid - 3584;
        int bx = idx >> 4, by = idx & 15;
        int tx = t & 31, ty = t >> 5;
        #pragma unroll
        for (int r = 0; r < 32; r += 8)
            tile[ty + r][tx] = Wnode[(size_t)(bx * 32 + ty + r) * DIM + by * 32 + tx];
        __syncthreads();
        #pragma unroll
        for (int r = 0; r < 32; r += 8)
            WnT[(size_t)(by * 32 + ty + r) * DIM + bx * 32 + tx] = f2bf(tile[tx][ty + r]);
        return;
    }
    if (bid >= 2048) {            // ---- Wih/Whh converts (768 blocks each, float4) ----
        int isW2 = bid >= 2816;
        int i4 = (bid - (isW2 ? 2816 : 2048)) * 256 + t;
        const float* src = isW2 ? Whh : Wih;
        unsigned short* dst = isW2 ? Whhb : Wihb;
        floatx4 a = *reinterpret_cast<const floatx4*>(src + (size_t)i4 * 4);
        ushort4 o;
        o.x = f2bf(a[0]); o.y = f2bf(a[1]); o.z = f2bf(a[2]); o.w = f2bf(a[3]);
        *reinterpret_cast<ushort4*>(dst + (size_t)i4 * 4) = o;
        return;
    }

    // ---- per-graph init ----
    __shared__ float wl[DIM];
    __shared__ float red[4 * DIM];
    int b = bid;
    wl[t] = watl[t]; wl[t + 256] = watl[t + 256];
    int s = lbound(seg, b), e = lbound(seg, b + 1);
    if (t == 0) {
        starts[b] = s;
        if (b == NGRAPH - 1) starts[NGRAPH] = e;
    }
    __syncthreads();
    int w = t >> 6, lane = t & 63;
    int f0 = lane * 4;
    float acc[8] = {0.f,0.f,0.f,0.f,0.f,0.f,0.f,0.f};

    auto proc = [&](int i, floatx4 v0, floatx4 v1) {
        acc[0] += v0[0]; acc[1] += v0[1]; acc[2] += v0[2]; acc[3] += v0[3];
        acc[4] += v1[0]; acc[5] += v1[1]; acc[6] += v1[2]; acc[7] += v1[3];
        float dot = v0[0]*wl[f0] + v0[1]*wl[f0+1] + v0[2]*wl[f0+2] + v0[3]*wl[f0+3]
                  + v1[0]*wl[256+f0] + v1[1]*wl[256+f0+1] + v1[2]*wl[256+f0+2] + v1[3]*wl[256+f0+3];
        #pragma unroll
        for (int off = 32; off > 0; off >>= 1) dot += __shfl_xor(dot, off);
        if (lane == 0) left_att[i] = dot;
        if constexpr (WRITE_XQ) {
            unsigned int q0 = (unsigned int)__builtin_amdgcn_cvt_pk_fp8_f32(v0[0], v0[1], 0, false);
            q0 = (unsigned int)__builtin_amdgcn_cvt_pk_fp8_f32(v0[2], v0[3], (int)q0, true);
            unsigned int q1 = (unsigned int)__builtin_amdgcn_cvt_pk_fp8_f32(v1[0], v1[1], 0, false);
            q1 = (unsigned int)__builtin_amdgcn_cvt_pk_fp8_f32(v1[2], v1[3], (int)q1, true);
            *reinterpret_cast<unsigned int*>(xq + (size_t)i * DIM + f0) = q0;
            *reinterpret_cast<unsigned int*>(xq + (size_t)i * DIM + 256 + f0) = q1;
        }
    };

    int i = s + w;
    for (; i + 4 < e; i += 8) {
        floatx4 a0 = __builtin_nontemporal_load(reinterpret_cast<const floatx4*>(x + (size_t)i * DIM + f0));
        floatx4 a1 = __builtin_nontemporal_load(reinterpret_cast<const floatx4*>(x + (size_t)i * DIM + 256 + f0));
        floatx4 b0 = __builtin_nontemporal_load(reinterpret_cast<const floatx4*>(x + (size_t)(i + 4) * DIM + f0));
        floatx4 b1 = __builtin_nontemporal_load(reinterpret_cast<const floatx4*>(x + (size_t)(i + 4) * DIM + 256 + f0));
        proc(i, a0, a1);
        proc(i + 4, b0, b1);
    }
    if (i < e) {
        floatx4 a0 = __builtin_nontemporal_load(reinterpret_cast<const floatx4*>(x + (size_t)i * DIM + f0));
        floatx4 a1 = __builtin_nontemporal_load(reinterpret_cast<const floatx4*>(x + (size_t)i * DIM + 256 + f0));
        proc(i, a0, a1);
    }

    #pragma unroll
    for (int j = 0; j < 4; j++) {
        red[w * DIM + f0 + j]       = acc[j];
        red[w * DIM + 256 + f0 + j] = acc[4 + j];
    }
    __syncthreads();
    float s0 = red[t]       + red[DIM + t]       + red[2*DIM + t]       + red[3*DIM + t];
    float s1 = red[256 + t] + red[DIM + 256 + t] + red[2*DIM + 256 + t] + red[3*DIM + 256 + t];
    hcur[(size_t)b * DIM + t] = s0;
    hcur[(size_t)b * DIM + 256 + t] = s1;
    hcur_bf[(size_t)b * DIM + t] = f2bf(s0);
    hcur_bf[(size_t)b * DIM + 256 + t] = f2bf(s1);
}

// ============ K2: fused attention (+ optional GRU gate of previous timestep) ============
template<bool XQ, bool FUSE_GATE>
__global__ __launch_bounds__(256) void k_att(const float* __restrict__ x,
        const unsigned char* __restrict__ xq, const float* __restrict__ left,
        const int* __restrict__ starts, float* __restrict__ hcur,
        unsigned short* __restrict__ hcurbf,
        const float* __restrict__ gi, const float* __restrict__ gh,
        const float* __restrict__ bih, const float* __restrict__ bhh,
        const float* __restrict__ watr, unsigned short* __restrict__ swbf) {
    __shared__ float red[4 * DIM];
    __shared__ float rsh[4];
    __shared__ float rsm[4];
    __shared__ float rscal[4];
    int b = blockIdx.x, t = threadIdx.x;
    int w = t >> 6, lane = t & 63;

    float p;
    if constexpr (FUSE_GATE) {
        // gate for graph b, elems j = t and j2 = t + 256 (block-exclusive row)
        size_t gb = (size_t)b * HID3;
        float o01[2];
        #pragma unroll
        for (int half = 0; half < 2; ++half) {
            int j = t + half * 256;
            float gir = gi[gb + j]        + bih[j];
            float giz = gi[gb + 512 + j]  + bih[512 + j];
            float gin = gi[gb + 1024 + j] + bih[1024 + j];
            float ghr = gh[gb + j]        + bhh[j];
            float ghz = gh[gb + 512 + j]  + bhh[512 + j];
            float ghn = gh[gb + 1024 + j] + bhh[1024 + j];
            float rg = 1.0f / (1.0f + __expf(-(gir + ghr)));
            float zg = 1.0f / (1.0f + __expf(-(giz + ghz)));
            float nn = tanhf(gin + rg * ghn);
            float hp = hcur[(size_t)b * DIM + j];
            float nh = (1.0f - zg) * nn + zg * hp;
            float o = nh / (1.0f + __expf(-nh));
            hcur[(size_t)b * DIM + j] = o;
            hcurbf[(size_t)b * DIM + j] = f2bf(o);
            o01[half] = o;
        }
        p = o01[0] * watr[t] + o01[1] * watr[t + 256];
    } else {
        p = hcur[(size_t)b * DIM + t] * watr[t] + hcur[(size_t)b * DIM + 256 + t] * watr[256 + t];
    }
    #pragma unroll
    for (int off = 32; off > 0; off >>= 1) p += __shfl_xor(p, off);
    if (lane == 0) rsh[w] = p;
    int s = starts[b], e = starts[b + 1];
    __syncthreads();
    float ra = rsh[0] + rsh[1] + rsh[2] + rsh[3];

    float m = -1e30f;
    for (int i = s + t; i < e; i += 256) {
        float a = left[i] + ra; a = a >= 0.f ? a : 0.01f * a;
        m = fmaxf(m, a);
    }
    #pragma unroll
    for (int off = 32; off > 0; off >>= 1) m = fmaxf(m, __shfl_xor(m, off));
    if (lane == 0) rsm[w] = m;
    __syncthreads();
    m = fmaxf(fmaxf(rsm[0], rsm[1]), fmaxf(rsm[2], rsm[3]));

    float acc[8] = {0.f,0.f,0.f,0.f,0.f,0.f,0.f,0.f};
    float esum = 0.f;
    if constexpr (XQ) {
        int f0 = lane * 8;
        auto qacc = [&](uint2 q, float ev) {
            floatx2 p0 = __builtin_amdgcn_cvt_pk_f32_fp8((int)q.x, false);
            floatx2 p1 = __builtin_amdgcn_cvt_pk_f32_fp8((int)q.x, true);
            floatx2 p2 = __builtin_amdgcn_cvt_pk_f32_fp8((int)q.y, false);
            floatx2 p3 = __builtin_amdgcn_cvt_pk_f32_fp8((int)q.y, true);
            acc[0] += ev * p0[0]; acc[1] += ev * p0[1];
            acc[2] += ev * p1[0]; acc[3] += ev * p1[1];
            acc[4] += ev * p2[0]; acc[5] += ev * p2[1];
            acc[6] += ev * p3[0]; acc[7] += ev * p3[1];
        };
        int i = s + w;
        for (; i + 4 < e; i += 8) {
            uint2 q0 = *reinterpret_cast<const uint2*>(xq + (size_t)i * DIM + f0);
            uint2 q1 = *reinterpret_cast<const uint2*>(xq + (size_t)(i + 4) * DIM + f0);
            float a0 = left[i] + ra;     a0 = a0 >= 0.f ? a0 : 0.01f * a0;
            float a1 = left[i + 4] + ra; a1 = a1 >= 0.f ? a1 : 0.01f * a1;
            float e0 = __expf(a0 - m), e1 = __expf(a1 - m);
            esum += e0 + e1;
            qacc(q0, e0);
            qacc(q1, e1);
        }
        if (i < e) {
            uint2 q0 = *reinterpret_cast<const uint2*>(xq + (size_t)i * DIM + f0);
            float a0 = left[i] + ra; a0 = a0 >= 0.f ? a0 : 0.01f * a0;
            float e0 = __expf(a0 - m);
            esum += e0;
            qacc(q0, e0);
        }
        #pragma unroll
        for (int j = 0; j < 8; j++) red[w * DIM + f0 + j] = acc[j];
    } else {
        int f0 = lane * 4;
        for (int i = s + w; i < e; i += 4) {
            float a0 = left[i] + ra; a0 = a0 >= 0.f ? a0 : 0.01f * a0;
            float e0 = __expf(a0 - m);
            esum += e0;
            float4 v0 = *reinterpret_cast<const float4*>(x + (size_t)i * DIM + f0);
            float4 v1 = *reinterpret_cast<const float4*>(x + (size_t)i * DIM + 256 + f0);
            acc[0] += e0 * v0.x; acc[1] += e0 * v0.y; acc[2] += e0 * v0.z; acc[3] += e0 * v0.w;
            acc[4] += e0 * v1.x; acc[5] += e0 * v1.y; acc[6] += e0 * v1.z; acc[7] += e0 * v1.w;
        }
        #pragma unroll
        for (int j = 0; j < 4; j++) {
            red[w * DIM + f0 + j]       = acc[j];
            red[w * DIM + 256 + f0 + j] = acc[4 + j];
        }
    }
    #pragma unroll
    for (int off = 32; off > 0; off >>= 1) esum += __shfl_xor(esum, off);
    if (lane == 0) rscal[w] = esum;
    __syncthreads();
    float tot = rscal[0] + rscal[1] + rscal[2] + rscal[3];
    float inv = tot > 0.f ? 1.0f / tot : 0.0f;
    float s0 = (red[t]       + red[DIM + t]       + red[2*DIM + t]       + red[3*DIM + t])       * inv;
    float s1 = (red[256 + t] + red[DIM + 256 + t] + red[2*DIM + 256 + t] + red[3*DIM + 256 + t]) * inv;
    swbf[(size_t)b * DIM + t] = f2bf(s0);
    swbf[(size_t)b * DIM + 256 + t] = f2bf(s1);
}

// ============ K3: bf16 MFMA GEMM, 2-phase pipeline, dual-problem z-select ============
__global__ __launch_bounds__(256, 2) void k_gemm(const unsigned short* __restrict__ A0,
        const unsigned short* __restrict__ Wt0, float* __restrict__ Cf0,
        unsigned short* __restrict__ Cb0, int Ncols0, int ny0,
        const unsigned short* __restrict__ A1, const unsigned short* __restrict__ Wt1,
        float* __restrict__ Cf1, unsigned short* __restrict__ Cb1, int Ncols1) {
    const int z = blockIdx.z;
    if (z == 0 && (int)blockIdx.y >= ny0) return;
    const unsigned short* A  = z ? A1  : A0;
    const unsigned short* Wt = z ? Wt1 : Wt0;
    float* Cf          = z ? Cf1 : Cf0;
    unsigned short* Cb = z ? Cb1 : Cb0;
    const int Ncols    = z ? Ncols1 : Ncols0;

    __shared__ __align__(16) unsigned short lA[2][128 * 64];
    __shared__ __align__(16) unsigned short lW[2][128 * 64];

    int t = threadIdx.x;
    int w = t >> 6, lane = t & 63;
    int wr = w >> 1, wc = w & 1;
    int mbase = blockIdx.x * 128;
    int nbase = blockIdx.y * 128;
    int fr = lane & 15, hi = lane >> 4;
    int swz_r = (fr & 7) << 4;

    int rbase = t >> 3;
    int cole = ((((t & 7) * 16) ^ ((rbase & 7) << 4)) >> 1);
    int ldsoff = t * 16;

    floatx4 acc[4][4];
    #pragma unroll
    for (int m = 0; m < 4; m++)
        #pragma unroll
        for (int n = 0; n < 4; n++) {
            acc[m][n][0] = 0.f; acc[m][n][1] = 0.f; acc[m][n][2] = 0.f; acc[m][n][3] = 0.f;
        }

    const unsigned short* gA = A  + (size_t)(mbase + rbase) * DIM + cole;
    const unsigned short* gW = Wt + (size_t)(nbase + rbase) * DIM + cole;

    auto stage = [&](int kk, int buf) {
        #pragma unroll
        for (int c = 0; c < 4; ++c) {
            gload_lds16(gA + (size_t)(c * 32) * DIM + kk, (char*)&lA[buf][0] + c * 4096 + ldsoff);
            gload_lds16(gW + (size_t)(c * 32) * DIM + kk, (char*)&lW[buf][0] + c * 4096 + ldsoff);
        }
    };

    stage(0, 0);
    __syncthreads();
    int cur = 0;
    for (int it = 0; it < 8; ++it) {
        if (it < 7) stage((it + 1) * 64, cur ^ 1);
        #pragma unroll
        for (int ks = 0; ks < 2; ++ks) {
            short8 af[4], bf[4];
            int bc = (ks * 64 + hi * 16) ^ swz_r;
            #pragma unroll
            for (int m = 0; m < 4; ++m) {
                int row = wr * 64 + m * 16 + fr;
                af[m] = *reinterpret_cast<const short8*>(&lA[cur][(row * 128 + bc) >> 1]);
            }
            #pragma unroll
            for (int n = 0; n < 4; ++n) {
                int row = wc * 64 + n * 16 + fr;
                bf[n] = *reinterpret_cast<const short8*>(&lW[cur][(row * 128 + bc) >> 1]);
            }
            #pragma unroll
            for (int m = 0; m < 4; ++m)
                #pragma unroll
                for (int n = 0; n < 4; ++n)
                    acc[m][n] = __builtin_amdgcn_mfma_f32_16x16x32_bf16(af[m], bf[n], acc[m][n], 0, 0, 0);
        }
        if (it < 7) __syncthreads();
        cur ^= 1;
    }

    int rq = hi * 4;
    #pragma unroll
    for (int m = 0; m < 4; m++) {
        #pragma unroll
        for (int n = 0; n < 4; n++) {
            int col = nbase + wc * 64 + n * 16 + fr;
            #pragma unroll
            for (int r = 0; r < 4; r++) {
                int row = mbase + wr * 64 + m * 16 + rq + r;
                float v = acc[m][n][r];
                if (Cb) {
                    v = v > 0.f ? v : (__expf(v) - 1.0f);
                    Cb[(size_t)row * Ncols + col] = f2bf(v);
                } else {
                    Cf[(size_t)row * Ncols + col] = v;
                }
            }
        }
    }
}

// ============ K4: final linear with fused GRU gate (ts1) prologue ============
__global__ __launch_bounds__(128) void k_fin(const float* __restrict__ hcur,
        const float* __restrict__ gi, const float* __restrict__ gh,
        const float* __restrict__ bih, const float* __restrict__ bhh,
        const float* __restrict__ Wlin, const float* __restrict__ blin,
        float* __restrict__ out) {
    __shared__ float rows[16 * DIM];
    int t = threadIdx.x;
    int b0 = blockIdx.x * 16;
    // gate for 16 graphs -> rows[] (hcur never written back)
    for (int k = 0; k < 16; ++k) {
        int i4 = t + k * 128;            // float4 index in [0, 2048)
        int bl = i4 >> 7;                // local graph 0..15
        int j  = (i4 & 127) << 2;        // 0..508
        size_t gb = (size_t)(b0 + bl) * HID3;
        floatx4 gir = *reinterpret_cast<const floatx4*>(gi + gb + j);
        floatx4 giz = *reinterpret_cast<const floatx4*>(gi + gb + 512 + j);
        floatx4 gin = *reinterpret_cast<const floatx4*>(gi + gb + 1024 + j);
        floatx4 ghr = *reinterpret_cast<const floatx4*>(gh + gb + j);
        floatx4 ghz = *reinterpret_cast<const floatx4*>(gh + gb + 512 + j);
        floatx4 ghn = *reinterpret_cast<const floatx4*>(gh + gb + 1024 + j);
        floatx4 bir = *reinterpret_cast<const floatx4*>(bih + j);
        floatx4 biz = *reinterpret_cast<const floatx4*>(bih + 512 + j);
        floatx4 bin = *reinterpret_cast<const floatx4*>(bih + 1024 + j);
        floatx4 bhr = *reinterpret_cast<const floatx4*>(bhh + j);
        floatx4 bhz = *reinterpret_cast<const floatx4*>(bhh + 512 + j);
        floatx4 bhn = *reinterpret_cast<const floatx4*>(bhh + 1024 + j);
        floatx4 hp  = *reinterpret_cast<const floatx4*>(hcur + (size_t)(b0 + bl) * DIM + j);
        floatx4 ov;
        #pragma unroll
        for (int r = 0; r < 4; r++) {
            float rg = 1.0f / (1.0f + __expf(-(gir[r] + bir[r] + ghr[r] + bhr[r])));
            float zg = 1.0f / (1.0f + __expf(-(giz[r] + biz[r] + ghz[r] + bhz[r])));
            float nn = tanhf(gin[r] + bin[r] + rg * (ghn[r] + bhn[r]));
            float nh = (1.0f - zg) * nn + zg * hp[r];
            ov[r] = nh / (1.0f + __expf(-nh));
        }
        *reinterpret_cast<floatx4*>(rows + (size_t)i4 * 4) = ov;
    }
    __syncthreads();
    float acc[16];
    #pragma unroll
    for (int r = 0; r < 16; r++) acc[r] = 0.f;
    #pragma unroll 4
    for (int k = 0; k < DIM; k++) {
        float wv = Wlin[k * OUTD + t];
        #pragma unroll
        for (int r = 0; r < 16; r++) acc[r] += rows[r * DIM + k] * wv;
    }
    float bl = blin[t];
    #pragma unroll
    for (int r = 0; r < 16; r++) out[(size_t)(b0 + r) * OUTD + t] = acc[r] + bl;
}

extern "C" void kernel_launch(void* const* d_in, const int* in_sizes, int n_in,
                              void* d_out, int out_size, void* d_ws, size_t ws_size,
                              hipStream_t stream) {
    const float* x     = (const float*)d_in[0];
    const int*   seg   = (const int*)d_in[1];
    const float* watl  = (const float*)d_in[2];
    const float* watr  = (const float*)d_in[3];
    const float* Wnode = (const float*)d_in[4];
    const float* Wih   = (const float*)d_in[5];
    const float* Whh   = (const float*)d_in[6];
    const float* bih   = (const float*)d_in[7];
    const float* bhh   = (const float*)d_in[8];
    const float* Wlin  = (const float*)d_in[9];
    const float* blin  = (const float*)d_in[10];
    float* out = (float*)d_out;

    char* ws = (char*)d_ws;
    size_t off = 0;
    auto alloc = [&](size_t bytes) -> void* {
        void* p = ws + off;
        off += bytes;
        off = (off + 255) & ~(size_t)255;
        return p;
    };
    float*          left    = (float*)          alloc((size_t)N_NODES * sizeof(float));
    float*          hcur    = (float*)          alloc((size_t)NGRAPH * DIM * sizeof(float));
    unsigned short* hcurbf  = (unsigned short*) alloc((size_t)NGRAPH * DIM * 2);
    unsigned short* hgbf    = (unsigned short*) alloc((size_t)NGRAPH * DIM * 2);
    unsigned short* swbf    = (unsigned short*) alloc((size_t)NGRAPH * DIM * 2);
    float*          gi      = (float*)          alloc((size_t)NGRAPH * HID3 * sizeof(float));
    float*          gh      = (float*)          alloc((size_t)NGRAPH * HID3 * sizeof(float));
    unsigned short* WnT     = (unsigned short*) alloc((size_t)DIM * DIM * 2);
    unsigned short* Wihb    = (unsigned short*) alloc((size_t)HID3 * DIM * 2);
    unsigned short* Whhb    = (unsigned short*) alloc((size_t)HID3 * DIM * 2);
    int*            starts  = (int*)            alloc((NGRAPH + 1) * sizeof(int));
    unsigned char*  xq      = (unsigned char*)(ws + off);
    bool use_xq = (off + (size_t)N_NODES * DIM) <= ws_size;

    if (use_xq)
        k_init<true ><<<3840, 256, 0, stream>>>(x, seg, watl, Wih, Whh, Wnode,
                left, hcur, hcurbf, xq, Wihb, Whhb, WnT, starts);
    else
        k_init<false><<<3840, 256, 0, stream>>>(x, seg, watl, Wih, Whh, Wnode,
                left, hcur, hcurbf, nullptr, Wihb, Whhb, WnT, starts);

    for (int ts = 0; ts < 2; ts++) {
        if (use_xq) {
            if (ts == 0)
                k_att<true , false><<<NGRAPH, 256, 0, stream>>>(x, xq, left, starts,
                        hcur, hcurbf, gi, gh, bih, bhh, watr, swbf);
            else
                k_att<true , true ><<<NGRAPH, 256, 0, stream>>>(x, xq, left, starts,
                        hcur, hcurbf, gi, gh, bih, bhh, watr, swbf);
        } else {
            if (ts == 0)
                k_att<false, false><<<NGRAPH, 256, 0, stream>>>(x, xq, left, starts,
                        hcur, hcurbf, gi, gh, bih, bhh, watr, swbf);
            else
                k_att<false, true ><<<NGRAPH, 256, 0, stream>>>(x, xq, left, starts,
                        hcur, hcurbf, gi, gh, bih, bhh, watr, swbf);
        }
        // launch A: z=0 -> hg = elu(sw @ WnT^T) [16x4], z=1 -> gh = h @ Whh^T [16x12]
        k_gemm<<<dim3(NGRAPH / 128, HID3 / 128, 2), 256, 0, stream>>>(
            swbf, WnT, nullptr, hgbf, DIM, DIM / 128,
            hcurbf, Whhb, gh, nullptr, HID3);
        // launch B: gi = hg @ Wih^T [16x12]
        k_gemm<<<dim3(NGRAPH / 128, HID3 / 128, 1), 256, 0, stream>>>(
            hgbf, Wihb, gi, nullptr, HID3, HID3 / 128,
            nullptr, nullptr, nullptr, nullptr, 0);
    }
    k_fin<<<NGRAPH / 16, 128, 0, stream>>>(hcur, gi, gh, bih, bhh, Wlin, blin, out);
}